// Round 1
// 4545.652 us; speedup vs baseline: 2.2821x; 2.2821x over previous
//
#include <hip/hip_runtime.h>
#include <hip/hip_cooperative_groups.h>

namespace cg = cooperative_groups;

#define B_ 64
#define T_ 1024
#define I_ 512
#define H_ 768
#define O_ 512
#define G4 3072          // 4*H
#define JB 16            // j-columns per workgroup
#define NWG 48           // workgroups per direction (H/JB)
#define NWGS 96          // total workgroups

typedef short short8 __attribute__((ext_vector_type(8)));
typedef float f32x4 __attribute__((ext_vector_type(4)));
typedef int int4v __attribute__((ext_vector_type(4)));
typedef unsigned long long u64;

// ws layout (bytes):
//   xb  : [T][64 kb][64 b][8] bf16 (k-blocked)            = 67,108,864 B
//   w2  : [2 dir][160 kb][3072 row][8] bf16 (k-blocked)   = 15,728,640 B
//   h2  : [2 dir][2 ring][96 kb][64 b][8] bf16            =    393,216 B
//   bar : 16 counters, 128-B stride                        =      2,048 B
#define XBF_BYTES  (67108864)
#define WCAT_BYTES (15728640)
#define HBUF_BYTES (393216)

__device__ __forceinline__ unsigned short f32_to_bf16(float f) {
    union { float f; unsigned int u; } v; v.f = f;
    unsigned int r = v.u + 0x7fffu + ((v.u >> 16) & 1u);
    return (unsigned short)(r >> 16);
}
__device__ __forceinline__ float sigmoid_f(float x) { return 1.0f / (1.0f + __expf(-x)); }
__device__ __forceinline__ float tanh_f(float x) {
    float e = __expf(2.0f * x);
    return 1.0f - 2.0f / (e + 1.0f);
}

// global (cached) -> LDS direct DMA, 16 B per lane. LDS dest must be
// wave-uniform base; HW writes base + lane*16 (linear lane order).
__device__ __forceinline__ void glds16(const void* g, void* l) {
    __builtin_amdgcn_global_load_lds(
        (const __attribute__((address_space(1))) unsigned int*)g,
        (__attribute__((address_space(3))) unsigned int*)l, 16, 0, 0);
}

// ---- prep: x (B,T,I) fp32 -> xb [t][kb][b][8] bf16 ---------------------------
__global__ void prep_x_kernel(const float* __restrict__ x, unsigned short* __restrict__ xb) {
    const size_t n = (size_t)B_ * T_ * 64;   // 4,194,304 chunks of 8
    for (size_t i = (size_t)blockIdx.x * blockDim.x + threadIdx.x; i < n;
         i += (size_t)gridDim.x * blockDim.x) {
        int b  = (int)(i >> 16);
        int t  = (int)((i >> 6) & 1023);
        int kb = (int)(i & 63);
        const float4 v0 = *(const float4*)(x + i * 8);
        const float4 v1 = *(const float4*)(x + i * 8 + 4);
        short8 o;
        o[0] = (short)f32_to_bf16(v0.x); o[1] = (short)f32_to_bf16(v0.y);
        o[2] = (short)f32_to_bf16(v0.z); o[3] = (short)f32_to_bf16(v0.w);
        o[4] = (short)f32_to_bf16(v1.x); o[5] = (short)f32_to_bf16(v1.y);
        o[6] = (short)f32_to_bf16(v1.z); o[7] = (short)f32_to_bf16(v1.w);
        *(short8*)(xb + (((size_t)t * 64 + kb) * 64 + b) * 8) = o;
    }
}

// ---- prep: weights fp32 -> w2 k-blocked bf16; zero h ring + counters ---------
__global__ void prep_w_kernel(const float* __restrict__ Wx_f, const float* __restrict__ Wh_f,
                              const float* __restrict__ Wx_b, const float* __restrict__ Wh_b,
                              unsigned short* __restrict__ w2, unsigned short* __restrict__ h2,
                              unsigned* __restrict__ bar) {
    const size_t n = (size_t)2 * G4 * 160;   // 983,040 chunks of 8 k
    for (size_t i = (size_t)blockIdx.x * blockDim.x + threadIdx.x; i < n;
         i += (size_t)gridDim.x * blockDim.x) {
        int dir = (int)(i / 491520);
        int r2  = (int)(i % 491520);
        int row = r2 / 160;
        int kb  = r2 % 160;
        const float* Wx = dir ? Wx_b : Wx_f;
        const float* Wh = dir ? Wh_b : Wh_f;
        const float* src = (kb < 64) ? (Wx + (size_t)row * I_ + kb * 8)
                                     : (Wh + (size_t)row * H_ + (kb - 64) * 8);
        const float4 v0 = *(const float4*)(src);
        const float4 v1 = *(const float4*)(src + 4);
        short8 o;
        o[0] = (short)f32_to_bf16(v0.x); o[1] = (short)f32_to_bf16(v0.y);
        o[2] = (short)f32_to_bf16(v0.z); o[3] = (short)f32_to_bf16(v0.w);
        o[4] = (short)f32_to_bf16(v1.x); o[5] = (short)f32_to_bf16(v1.y);
        o[6] = (short)f32_to_bf16(v1.z); o[7] = (short)f32_to_bf16(v1.w);
        *(short8*)(w2 + (((size_t)dir * 160 + kb) * G4 + row) * 8) = o;
        if (i < 24576) {   // zero all 4 h ring slots (393,216 B)
            short8 z = {0,0,0,0,0,0,0,0};
            *(short8*)(h2 + i * 8) = z;
        }
        if (i < 512) bar[i] = 0u;   // zero barrier counter region
    }
}

// ---- persistent BiLSTM recurrence ---------------------------------------------
// 96 wgs (2 dir x 48 j-blocks) x 512 thr (8 waves: gate x mhalf).
// astage (96 KB LDS) is time-multiplexed: x A-tile (64 KB, prefetched via
// global_load_lds during previous step's gate phase) then h_{t-1} (96 KB,
// staged with 12x16B sc1 loads, 6-deep explicit-vmcnt pipeline).
__global__ void __launch_bounds__(512, 2)
bilstm_kernel(const float* __restrict__ bias_f, const float* __restrict__ bias_b,
              const unsigned short* __restrict__ xb, const unsigned short* __restrict__ w2,
              unsigned short* h2, unsigned* bar, float* d_out) {
    __shared__ unsigned short astage[96 * 64 * 8];    // 98,304 B (x: first 64 KB)
    __shared__ float z_lds[4][64][17];                // 17,408 B
    __shared__ float c_tile[64][16];                  //  4,096 B

    const int tid   = threadIdx.x;
    const int wg    = blockIdx.x;
    const int dir   = wg / NWG;
    const int j0    = (wg % NWG) * JB;
    const int wave  = tid >> 6;
    const int lane  = tid & 63;
    const int gate  = wave & 3;      // f,i,g,o
    const int mhalf = wave >> 2;
    const int quad  = lane >> 4;
    const int lrow  = lane & 15;

    for (int i = tid; i < 1024; i += 512) c_tile[i >> 4][i & 15] = 0.0f;

    const float bias_r = (dir ? bias_b : bias_f)[gate * H_ + j0 + lrow];
    const int m0 = mhalf * 32 + lrow;
    const int wrow = gate * H_ + j0 + lrow;

    // x-weight base (kb = quad + 4*ks) — stays in L2 (no fences evict it)
    const unsigned short* wx = w2 + (((size_t)dir * 160 + quad) * G4 + wrow) * 8;
    // h-weights: register-resident, constant over all steps (96 VGPR)
    short8 wh[24];
#pragma unroll
    for (int ks = 0; ks < 24; ++ks)
        wh[ks] = *(const short8*)(w2 + (((size_t)dir * 160 + 64 + ks * 4 + quad) * G4 + wrow) * 8);

    // striped barrier: 8 counters per dir, 128-B apart
    unsigned* mybar = bar + (dir * 8 + (wg & 7)) * 32;
    unsigned* barbase = bar + dir * 8 * 32;

    // gate-phase mapping: thread -> (b, pair of j)
    const int gb = tid >> 3;
    const int gj = (tid & 7) * 2;
    const int gjj = j0 + gj;

    // staging pointers
    char* const lds_wb   = (char*)astage + (tid >> 6) * 1024;   // wave-uniform DMA base
    char* const lds_mine = (char*)astage + tid * 16;
    const unsigned short* va = astage + quad * 512 + m0 * 8;    // A-fragment base (x and h)

    // prologue: stage x A-tile for t=0
    {
        const int tx0 = dir ? (T_ - 1) : 0;
        const char* xsrc = (const char*)(xb + (size_t)tx0 * 32768) + tid * 16;
#pragma unroll
        for (int k = 0; k < 8; ++k) glds16(xsrc + k * 8192, lds_wb + k * 8192);
    }
    __syncthreads();

    for (int t = 0; t < T_; ++t) {
        const int pb = (t + 1) & 1;
        const int cb = t & 1;

        f32x4 acc0; acc0[0] = bias_r; acc0[1] = bias_r; acc0[2] = bias_r; acc0[3] = bias_r;
        f32x4 acc1 = acc0;

        // ---- x-part from LDS (staged during previous gate phase) -------------
#pragma unroll
        for (int ks = 0; ks < 16; ++ks) {
            short8 a0 = *(const short8*)(va + ks * 2048);
            short8 a1 = *(const short8*)(va + ks * 2048 + 128);
            short8 bf = *(const short8*)(wx + (size_t)ks * 4 * G4 * 8);
            acc0 = __builtin_amdgcn_mfma_f32_16x16x32_bf16(a0, bf, acc0, 0, 0, 0);
            acc1 = __builtin_amdgcn_mfma_f32_16x16x32_bf16(a1, bf, acc1, 0, 0, 0);
        }

        // ---- wait: all wgs of my dir finished step t-1 (relaxed, no fence) ----
        if (tid == 0) {
            const unsigned tgt = (unsigned)(NWG * t);
            for (;;) {
                unsigned ssum = 0;
#pragma unroll
                for (int i = 0; i < 8; ++i)
                    ssum += __hip_atomic_load(barbase + i * 32, __ATOMIC_RELAXED,
                                              __HIP_MEMORY_SCOPE_AGENT);
                if (ssum >= tgt) break;
                __builtin_amdgcn_s_sleep(1);
            }
        }
        asm volatile("" ::: "memory");
        __syncthreads();   // (a) — also separates x-A LDS reads from h-stage writes

        // ---- stage h_{t-1} (96 KB): 12x16B device-coherent loads, 6-deep ----
        // (wave vmcnt == 0 here: all prior loads were consumed, stores drained)
        {
            const char* hp = (const char*)(h2 + (size_t)(dir * 2 + pb) * 49152) + tid * 16;
            int4v u0, u1, u2, u3, u4, u5, u6, u7, u8, u9, u10, u11;
#define HL(n) asm volatile("global_load_dwordx4 %0, %1, off sc1" : "=v"(u##n) : "v"(hp + (n) * 8192))
#define HS(n) *(int4v*)(lds_mine + (n) * 8192) = u##n
            HL(0); HL(1); HL(2); HL(3); HL(4); HL(5);
            asm volatile("s_waitcnt vmcnt(5)" ::: "memory"); HS(0); HL(6);
            asm volatile("s_waitcnt vmcnt(5)" ::: "memory"); HS(1); HL(7);
            asm volatile("s_waitcnt vmcnt(5)" ::: "memory"); HS(2); HL(8);
            asm volatile("s_waitcnt vmcnt(5)" ::: "memory"); HS(3); HL(9);
            asm volatile("s_waitcnt vmcnt(5)" ::: "memory"); HS(4); HL(10);
            asm volatile("s_waitcnt vmcnt(5)" ::: "memory"); HS(5); HL(11);
            asm volatile("s_waitcnt vmcnt(5)" ::: "memory"); HS(6);
            asm volatile("s_waitcnt vmcnt(4)" ::: "memory"); HS(7);
            asm volatile("s_waitcnt vmcnt(3)" ::: "memory"); HS(8);
            asm volatile("s_waitcnt vmcnt(2)" ::: "memory"); HS(9);
            asm volatile("s_waitcnt vmcnt(1)" ::: "memory"); HS(10);
            asm volatile("s_waitcnt vmcnt(0)" ::: "memory"); HS(11);
#undef HL
#undef HS
        }
        __syncthreads();   // (b)

        // ---- h-part: K = 768 recurrent, A-fragments from LDS (ds_read_b128) ----
#pragma unroll
        for (int ks = 0; ks < 24; ++ks) {
            short8 a0 = *(const short8*)(va + ks * 2048);
            short8 a1 = *(const short8*)(va + ks * 2048 + 128);
            acc0 = __builtin_amdgcn_mfma_f32_16x16x32_bf16(a0, wh[ks], acc0, 0, 0, 0);
            acc1 = __builtin_amdgcn_mfma_f32_16x16x32_bf16(a1, wh[ks], acc1, 0, 0, 0);
        }

        // z -> LDS (C layout: col=lane&15, row=quad*4+reg)
#pragma unroll
        for (int r = 0; r < 4; ++r) {
            z_lds[gate][mhalf * 32 + quad * 4 + r][lrow]      = acc0[r];
            z_lds[gate][mhalf * 32 + 16 + quad * 4 + r][lrow] = acc1[r];
        }
        __syncthreads();   // (c) — z visible; astage h-reads complete

        // ---- prefetch next step's x A-tile (DMA, overlaps gate phase) --------
        if (t + 1 < T_) {
            const int tx2 = dir ? (T_ - 2 - t) : (t + 1);
            const char* xsrc = (const char*)(xb + (size_t)tx2 * 32768) + tid * 16;
#pragma unroll
            for (int k = 0; k < 8; ++k) glds16(xsrc + k * 8192, lds_wb + k * 8192);
        }

        // ---- gates: thread handles (b, j..j+1), packed coherent 4-B store ----
        {
            unsigned short* hw = h2 + (size_t)(dir * 2 + cb) * 49152;
            float f0 = sigmoid_f(z_lds[0][gb][gj]);
            float f1 = sigmoid_f(z_lds[0][gb][gj + 1]);
            float i0 = sigmoid_f(z_lds[1][gb][gj]);
            float i1 = sigmoid_f(z_lds[1][gb][gj + 1]);
            float g0 = tanh_f(z_lds[2][gb][gj]);
            float g1 = tanh_f(z_lds[2][gb][gj + 1]);
            float o0 = sigmoid_f(z_lds[3][gb][gj]);
            float o1 = sigmoid_f(z_lds[3][gb][gj + 1]);
            float c0 = f0 * c_tile[gb][gj]     + i0 * g0;
            float c1 = f1 * c_tile[gb][gj + 1] + i1 * g1;
            c_tile[gb][gj]     = c0;
            c_tile[gb][gj + 1] = c1;
            float h0 = o0 * tanh_f(c0);
            float h1 = o1 * tanh_f(c1);
            unsigned pack = (unsigned)f32_to_bf16(h0) | ((unsigned)f32_to_bf16(h1) << 16);
            unsigned* dst = (unsigned*)(hw + ((gjj >> 3) * 64 + gb) * 8 + (gjj & 7));
            __hip_atomic_store(dst, pack, __ATOMIC_RELAXED, __HIP_MEMORY_SCOPE_AGENT);
            if (t == T_ - 1) {
                int hoff = 32768 + dir * 98304;
                d_out[hoff + gb * H_ + gjj]             = h0;
                d_out[hoff + gb * H_ + gjj + 1]         = h1;
                d_out[hoff + 49152 + gb * H_ + gjj]     = c0;
                d_out[hoff + 49152 + gb * H_ + gjj + 1] = c1;
            }
        }
        __syncthreads();   // (d) — drains h stores (coherence point) + x DMA

        // ---- arrive (relaxed add to this wg's stripe) ----
        if (tid == 0)
            __hip_atomic_fetch_add(mybar, 1u, __ATOMIC_RELAXED, __HIP_MEMORY_SCOPE_AGENT);
    }
}

// ---- epilogue: out = [h_fwd|h_bwd] @ Why^T + by ------------------------------
__global__ void proj_kernel(float* __restrict__ out, const float* __restrict__ Why,
                            const float* __restrict__ by) {
    __shared__ float hc[2 * H_];
    int b = blockIdx.x;
    const float* hf = out + 32768 + b * H_;
    const float* hb = out + 32768 + 98304 + b * H_;
    for (int i = threadIdx.x; i < H_; i += 256) { hc[i] = hf[i]; hc[H_ + i] = hb[i]; }
    __syncthreads();
    for (int o = threadIdx.x; o < O_; o += 256) {
        const float* wr = Why + (size_t)o * (2 * H_);
        float s = by[o];
        for (int k = 0; k < 2 * H_; k += 4) {
            float4 w = *(const float4*)(wr + k);
            s += w.x * hc[k] + w.y * hc[k + 1] + w.z * hc[k + 2] + w.w * hc[k + 3];
        }
        out[b * O_ + o] = s;
    }
}

extern "C" void kernel_launch(void* const* d_in, const int* in_sizes, int n_in,
                              void* d_out, int out_size, void* d_ws, size_t ws_size,
                              hipStream_t stream) {
    const float* x    = (const float*)d_in[0];
    const float* Wx_f = (const float*)d_in[1];
    const float* Wh_f = (const float*)d_in[2];
    const float* b_f  = (const float*)d_in[3];
    const float* Wx_b = (const float*)d_in[4];
    const float* Wh_b = (const float*)d_in[5];
    const float* b_b  = (const float*)d_in[6];
    const float* Why  = (const float*)d_in[7];
    const float* by   = (const float*)d_in[8];
    float* out = (float*)d_out;

    char* ws = (char*)d_ws;
    unsigned short* xbp = (unsigned short*)(ws);
    unsigned short* w2  = (unsigned short*)(ws + XBF_BYTES);
    unsigned short* h2  = (unsigned short*)(ws + XBF_BYTES + WCAT_BYTES);
    unsigned*       bar = (unsigned*)(ws + XBF_BYTES + WCAT_BYTES + HBUF_BYTES);

    prep_x_kernel<<<8192, 256, 0, stream>>>(x, xbp);
    prep_w_kernel<<<4096, 256, 0, stream>>>(Wx_f, Wh_f, Wx_b, Wh_b, w2, h2, bar);

    void* args[] = {(void*)&b_f, (void*)&b_b, (void*)&xbp, (void*)&w2,
                    (void*)&h2, (void*)&bar, (void*)&out};
    hipLaunchCooperativeKernel((void*)bilstm_kernel, dim3(NWGS), dim3(512), args, 0, stream);

    proj_kernel<<<B_, 256, 0, stream>>>(out, Why, by);
}

// Round 2
// 3024.336 us; speedup vs baseline: 3.4301x; 1.5030x over previous
//
#include <hip/hip_runtime.h>
#include <hip/hip_cooperative_groups.h>

namespace cg = cooperative_groups;

#define B_ 64
#define T_ 1024
#define I_ 512
#define H_ 768
#define O_ 512
#define G4 3072          // 4*H
#define JB 16            // j-columns per workgroup
#define NJ 48            // j-blocks per direction (H/JB)
#define NWGS 192         // 2 dir x 2 batch-half x 48 j-blocks

typedef short short8 __attribute__((ext_vector_type(8)));
typedef float f32x4 __attribute__((ext_vector_type(4)));
typedef int int4v __attribute__((ext_vector_type(4)));
typedef unsigned long long u64;

// ws layout (bytes):
//   xb  : [T][64 kb][64 b][8] bf16 (k-blocked)            = 67,108,864 B
//   w2  : [2 dir][160 kb][3072 row][8] bf16 (k-blocked)   = 15,728,640 B
//   h2  : [2 dir][2 ring][96 kb][64 b][8] bf16            =    393,216 B
//   bar : 16 counters (4 groups x 4 stripes), 128-B apart =      2,048 B
#define XBF_BYTES  (67108864)
#define WCAT_BYTES (15728640)
#define HBUF_BYTES (393216)

__device__ __forceinline__ unsigned short f32_to_bf16(float f) {
    union { float f; unsigned int u; } v; v.f = f;
    unsigned int r = v.u + 0x7fffu + ((v.u >> 16) & 1u);
    return (unsigned short)(r >> 16);
}
__device__ __forceinline__ float sigmoid_f(float x) { return 1.0f / (1.0f + __expf(-x)); }
__device__ __forceinline__ float tanh_f(float x) {
    float e = __expf(2.0f * x);
    return 1.0f - 2.0f / (e + 1.0f);
}

// global (cached) -> LDS direct DMA, 16 B per lane. LDS dest is wave-uniform
// base; HW writes base + lane*16 (linear lane order). Global src is per-lane.
__device__ __forceinline__ void glds16(const void* g, void* l) {
    __builtin_amdgcn_global_load_lds(
        (const __attribute__((address_space(1))) unsigned int*)g,
        (__attribute__((address_space(3))) unsigned int*)l, 16, 0, 0);
}

// raw workgroup barrier with LDS-only drain: does NOT drain vmcnt, so
// in-flight global_load_lds DMA survives across it.
__device__ __forceinline__ void ldsbar() {
    asm volatile("s_waitcnt lgkmcnt(0)" ::: "memory");
    __builtin_amdgcn_sched_barrier(0);
    __builtin_amdgcn_s_barrier();
    __builtin_amdgcn_sched_barrier(0);
}

// ---- prep: x (B,T,I) fp32 -> xb [t][kb][b][8] bf16 ---------------------------
__global__ void prep_x_kernel(const float* __restrict__ x, unsigned short* __restrict__ xb) {
    const size_t n = (size_t)B_ * T_ * 64;   // 4,194,304 chunks of 8
    for (size_t i = (size_t)blockIdx.x * blockDim.x + threadIdx.x; i < n;
         i += (size_t)gridDim.x * blockDim.x) {
        int b  = (int)(i >> 16);
        int t  = (int)((i >> 6) & 1023);
        int kb = (int)(i & 63);
        const float4 v0 = *(const float4*)(x + i * 8);
        const float4 v1 = *(const float4*)(x + i * 8 + 4);
        short8 o;
        o[0] = (short)f32_to_bf16(v0.x); o[1] = (short)f32_to_bf16(v0.y);
        o[2] = (short)f32_to_bf16(v0.z); o[3] = (short)f32_to_bf16(v0.w);
        o[4] = (short)f32_to_bf16(v1.x); o[5] = (short)f32_to_bf16(v1.y);
        o[6] = (short)f32_to_bf16(v1.z); o[7] = (short)f32_to_bf16(v1.w);
        *(short8*)(xb + (((size_t)t * 64 + kb) * 64 + b) * 8) = o;
    }
}

// ---- prep: weights fp32 -> w2 k-blocked bf16; zero h ring + counters ---------
__global__ void prep_w_kernel(const float* __restrict__ Wx_f, const float* __restrict__ Wh_f,
                              const float* __restrict__ Wx_b, const float* __restrict__ Wh_b,
                              unsigned short* __restrict__ w2, unsigned short* __restrict__ h2,
                              unsigned* __restrict__ bar) {
    const size_t n = (size_t)2 * G4 * 160;   // 983,040 chunks of 8 k
    for (size_t i = (size_t)blockIdx.x * blockDim.x + threadIdx.x; i < n;
         i += (size_t)gridDim.x * blockDim.x) {
        int dir = (int)(i / 491520);
        int r2  = (int)(i % 491520);
        int row = r2 / 160;
        int kb  = r2 % 160;
        const float* Wx = dir ? Wx_b : Wx_f;
        const float* Wh = dir ? Wh_b : Wh_f;
        const float* src = (kb < 64) ? (Wx + (size_t)row * I_ + kb * 8)
                                     : (Wh + (size_t)row * H_ + (kb - 64) * 8);
        const float4 v0 = *(const float4*)(src);
        const float4 v1 = *(const float4*)(src + 4);
        short8 o;
        o[0] = (short)f32_to_bf16(v0.x); o[1] = (short)f32_to_bf16(v0.y);
        o[2] = (short)f32_to_bf16(v0.z); o[3] = (short)f32_to_bf16(v0.w);
        o[4] = (short)f32_to_bf16(v1.x); o[5] = (short)f32_to_bf16(v1.y);
        o[6] = (short)f32_to_bf16(v1.z); o[7] = (short)f32_to_bf16(v1.w);
        *(short8*)(w2 + (((size_t)dir * 160 + kb) * G4 + row) * 8) = o;
        if (i < 24576) {   // zero all 4 h ring slots (393,216 B)
            short8 z = {0,0,0,0,0,0,0,0};
            *(short8*)(h2 + i * 8) = z;
        }
        if (i < 512) bar[i] = 0u;   // zero barrier counter region (2,048 B)
    }
}

// ---- persistent BiLSTM recurrence ---------------------------------------------
// 192 wgs (2 dir x 2 batch-half x 48 j-blocks) x 512 thr (8 waves: gate x mhalf).
// Batch-split: each WG owns 32 batch rows -> h broadcast per WG is 48 KB (not
// 96 KB), h-MFMA halves, and 192 CUs share the same aggregate L3 traffic.
// Barrier groups: 4 independent (dir x bhalf) groups of 48 WGs.
__global__ void __launch_bounds__(512, 2)
bilstm_kernel(const float* __restrict__ bias_f, const float* __restrict__ bias_b,
              const unsigned short* __restrict__ xb, const unsigned short* __restrict__ w2,
              unsigned short* h2, unsigned* bar, float* d_out) {
    __shared__ unsigned short x_lds[64 * 32 * 8];     // 32,768 B  [kb][32 b][8]
    __shared__ unsigned short h_lds[96 * 32 * 8];     // 49,152 B  [kb][32 b][8]
    __shared__ float z_lds[4][32][17];                //  8,704 B
    __shared__ float c_tile[32][16];                  //  2,048 B

    const int tid   = threadIdx.x;
    const int wg    = blockIdx.x;
    const int dir   = wg / 96;
    const int rem   = wg % 96;
    const int bh    = rem / NJ;          // batch half: rows bh*32 .. bh*32+31
    const int jb    = rem % NJ;
    const int j0    = jb * JB;
    const int wave  = tid >> 6;
    const int lane  = tid & 63;
    const int gate  = wave & 3;          // f,i,g,o
    const int mhalf = wave >> 2;
    const int quad  = lane >> 4;
    const int lrow  = lane & 15;
    const int m0l   = mhalf * 16 + lrow; // local batch row 0..31

    c_tile[tid >> 4][tid & 15] = 0.0f;

    const float bias_r = (dir ? bias_b : bias_f)[gate * H_ + j0 + lrow];
    const int wrow = gate * H_ + j0 + lrow;

    // x-weight base (kb = quad + 4*ks) — stays in L2 (no fences evict it)
    const unsigned short* wx = w2 + (((size_t)dir * 160 + quad) * G4 + wrow) * 8;
    // h-weights: register-resident, constant over all steps (96 VGPR)
    short8 wh[24];
#pragma unroll
    for (int ks = 0; ks < 24; ++ks)
        wh[ks] = *(const short8*)(w2 + (((size_t)dir * 160 + 64 + ks * 4 + quad) * G4 + wrow) * 8);

    // striped barrier: 4 groups (dir x bh) x 4 stripes, 128-B apart
    const int group = dir * 2 + bh;
    unsigned* mybar = bar + (group * 4 + (jb & 3)) * 32;
    unsigned* barbase = bar + group * 4 * 32;

    // per-thread byte offset into a [kb][64 b][8] panel, selecting our 32 rows:
    // 16B unit u = tid + k*512 -> kb = u>>5, r = u&31, row = bh*32 + r
    const int src_off = (tid >> 5) * 1024 + bh * 512 + (tid & 31) * 16;

    char* const lds_wb   = (char*)x_lds + wave * 1024;   // wave-uniform DMA base
    char* const lds_mine = (char*)h_lds + tid * 16;
    const unsigned short* vax = x_lds + quad * 256 + m0l * 8;
    const unsigned short* vah = h_lds + quad * 256 + m0l * 8;

    // prologue: stage x tile (32 KB) for t=0
    {
        const int tx0 = dir ? (T_ - 1) : 0;
        const char* xsrc = (const char*)(xb + (size_t)tx0 * 32768) + src_off;
#pragma unroll
        for (int k = 0; k < 4; ++k) glds16(xsrc + k * 16384, lds_wb + k * 8192);
    }
    __syncthreads();

    for (int t = 0; t < T_; ++t) {
        const int pb = (t + 1) & 1;
        const int cb = t & 1;

        f32x4 acc0; acc0[0] = bias_r; acc0[1] = bias_r; acc0[2] = bias_r; acc0[3] = bias_r;

        // ---- x-part from LDS (staged by DMA during previous step) ------------
#pragma unroll
        for (int ks = 0; ks < 16; ++ks) {
            short8 a0 = *(const short8*)(vax + ks * 1024);
            short8 bf = *(const short8*)(wx + (size_t)ks * 4 * G4 * 8);
            acc0 = __builtin_amdgcn_mfma_f32_16x16x32_bf16(a0, bf, acc0, 0, 0, 0);
        }

        // ---- wait: all 48 wgs of my (dir,bh) group finished step t-1 ----------
        if (tid == 0) {
            const unsigned tgt = (unsigned)(NJ * t);
            for (;;) {
                unsigned ssum = 0;
#pragma unroll
                for (int i = 0; i < 4; ++i)
                    ssum += __hip_atomic_load(barbase + i * 32, __ATOMIC_RELAXED,
                                              __HIP_MEMORY_SCOPE_AGENT);
                if (ssum >= tgt) break;
                __builtin_amdgcn_s_sleep(1);
            }
        }
        asm volatile("" ::: "memory");
        __syncthreads();   // (a) full drain; vmcnt==0 entering h-stage

        // ---- stage h_{t-1} rows [bh*32..+31] (48 KB): 6x16B sc1 loads --------
        {
            const char* hp = (const char*)(h2 + (size_t)(dir * 2 + pb) * 49152) + src_off;
            int4v u0, u1, u2, u3, u4, u5;
#define HL(n) asm volatile("global_load_dwordx4 %0, %1, off sc1" : "=v"(u##n) : "v"(hp + (n) * 16384))
#define HS(n) *(int4v*)(lds_mine + (n) * 8192) = u##n
            HL(0); HL(1); HL(2); HL(3); HL(4); HL(5);
            asm volatile("s_waitcnt vmcnt(5)" ::: "memory"); HS(0);
            asm volatile("s_waitcnt vmcnt(4)" ::: "memory"); HS(1);
            asm volatile("s_waitcnt vmcnt(3)" ::: "memory"); HS(2);
            asm volatile("s_waitcnt vmcnt(2)" ::: "memory"); HS(3);
            asm volatile("s_waitcnt vmcnt(1)" ::: "memory"); HS(4);
            asm volatile("s_waitcnt vmcnt(0)" ::: "memory"); HS(5);
#undef HL
#undef HS
        }

        // ---- prefetch next step's x tile (DMA; in flight across (b),(c)) -----
        if (t + 1 < T_) {
            const int tx2 = dir ? (T_ - 2 - t) : (t + 1);
            const char* xsrc = (const char*)(xb + (size_t)tx2 * 32768) + src_off;
#pragma unroll
            for (int k = 0; k < 4; ++k) glds16(xsrc + k * 16384, lds_wb + k * 8192);
        }
        ldsbar();          // (b) LDS-only drain: h_lds visible, DMA survives

        // ---- h-part: K = 768 recurrent, A-fragments from LDS -----------------
#pragma unroll
        for (int ks = 0; ks < 24; ++ks) {
            short8 a0 = *(const short8*)(vah + ks * 1024);
            acc0 = __builtin_amdgcn_mfma_f32_16x16x32_bf16(a0, wh[ks], acc0, 0, 0, 0);
        }

        // z -> LDS (C layout: col=lane&15, row=quad*4+reg)
#pragma unroll
        for (int r = 0; r < 4; ++r)
            z_lds[gate][mhalf * 16 + quad * 4 + r][lrow] = acc0[r];
        ldsbar();          // (c) z visible, DMA still in flight

        // ---- gates: thread handles one (b,j); pair-pack via shfl -------------
        {
            unsigned short* hw = h2 + (size_t)(dir * 2 + cb) * 49152;
            const int gb  = tid >> 4;
            const int gj  = tid & 15;
            const int gjj = j0 + gj;
            const int bg  = bh * 32 + gb;
            float f0 = sigmoid_f(z_lds[0][gb][gj]);
            float i0 = sigmoid_f(z_lds[1][gb][gj]);
            float g0 = tanh_f(z_lds[2][gb][gj]);
            float o0 = sigmoid_f(z_lds[3][gb][gj]);
            float c0 = f0 * c_tile[gb][gj] + i0 * g0;
            c_tile[gb][gj] = c0;
            float h0 = o0 * tanh_f(c0);
            unsigned hv = (unsigned)f32_to_bf16(h0);
            unsigned ov = __shfl_xor(hv, 1);
            if (!(gj & 1)) {
                unsigned pack = hv | (ov << 16);
                unsigned* dst = (unsigned*)(hw + ((gjj >> 3) * 64 + bg) * 8 + (gjj & 7));
                __hip_atomic_store(dst, pack, __ATOMIC_RELAXED, __HIP_MEMORY_SCOPE_AGENT);
            }
            if (t == T_ - 1) {
                int hoff = 32768 + dir * 98304;
                d_out[hoff + bg * H_ + gjj]         = h0;
                d_out[hoff + 49152 + bg * H_ + gjj] = c0;
            }
        }
        __syncthreads();   // (d) drains h stores (coherence point) + x DMA

        // ---- arrive (relaxed add to this wg's stripe) ----
        if (tid == 0)
            __hip_atomic_fetch_add(mybar, 1u, __ATOMIC_RELAXED, __HIP_MEMORY_SCOPE_AGENT);
    }
}

// ---- epilogue: out = [h_fwd|h_bwd] @ Why^T + by ------------------------------
__global__ void proj_kernel(float* __restrict__ out, const float* __restrict__ Why,
                            const float* __restrict__ by) {
    __shared__ float hc[2 * H_];
    int b = blockIdx.x;
    const float* hf = out + 32768 + b * H_;
    const float* hb = out + 32768 + 98304 + b * H_;
    for (int i = threadIdx.x; i < H_; i += 256) { hc[i] = hf[i]; hc[H_ + i] = hb[i]; }
    __syncthreads();
    for (int o = threadIdx.x; o < O_; o += 256) {
        const float* wr = Why + (size_t)o * (2 * H_);
        float s = by[o];
        for (int k = 0; k < 2 * H_; k += 4) {
            float4 w = *(const float4*)(wr + k);
            s += w.x * hc[k] + w.y * hc[k + 1] + w.z * hc[k + 2] + w.w * hc[k + 3];
        }
        out[b * O_ + o] = s;
    }
}

extern "C" void kernel_launch(void* const* d_in, const int* in_sizes, int n_in,
                              void* d_out, int out_size, void* d_ws, size_t ws_size,
                              hipStream_t stream) {
    const float* x    = (const float*)d_in[0];
    const float* Wx_f = (const float*)d_in[1];
    const float* Wh_f = (const float*)d_in[2];
    const float* b_f  = (const float*)d_in[3];
    const float* Wx_b = (const float*)d_in[4];
    const float* Wh_b = (const float*)d_in[5];
    const float* b_b  = (const float*)d_in[6];
    const float* Why  = (const float*)d_in[7];
    const float* by   = (const float*)d_in[8];
    float* out = (float*)d_out;

    char* ws = (char*)d_ws;
    unsigned short* xbp = (unsigned short*)(ws);
    unsigned short* w2  = (unsigned short*)(ws + XBF_BYTES);
    unsigned short* h2  = (unsigned short*)(ws + XBF_BYTES + WCAT_BYTES);
    unsigned*       bar = (unsigned*)(ws + XBF_BYTES + WCAT_BYTES + HBUF_BYTES);

    prep_x_kernel<<<8192, 256, 0, stream>>>(x, xbp);
    prep_w_kernel<<<4096, 256, 0, stream>>>(Wx_f, Wh_f, Wx_b, Wh_b, w2, h2, bar);

    void* args[] = {(void*)&b_f, (void*)&b_b, (void*)&xbp, (void*)&w2,
                    (void*)&h2, (void*)&bar, (void*)&out};
    hipLaunchCooperativeKernel((void*)bilstm_kernel, dim3(NWGS), dim3(512), args, 0, stream);

    proj_kernel<<<B_, 256, 0, stream>>>(out, Why, by);
}